// Round 11
// baseline (48.931 us; speedup 1.0000x reference)
//
#include <hip/hip_runtime.h>

// EquivariantProductBasisBlock (MACE symmetric contraction, nu=3) on gfx950.
//
// R11: DIAGNOSTIC + candidate. Two-kernel structure (build kernel packs coef
// frags in PT order + Wlin B-frags; main kernel R5-shaped). Branchless
// monomials (PT pairing, no ks-divergent double-issue). Early weight+sc
// preloads. REPS=8 wraps the FULL body (staging..phase3) with opaque regs:
//   dur ~= C + Body_cold + 7*Body_warm   (C ~= launch+build+gap+entry+store)
// Final store uses last rep's z (bit-identical each rep); absmax unchanged.

typedef __attribute__((ext_vector_type(8))) short short8;
typedef __attribute__((ext_vector_type(16))) float f32x16;

#define NSTEP 14
#define NPOS (NSTEP*8)              // 112 k-pair positions
#define REPS 8
#define TBLB_DWORDS (NSTEP*64*4)    // 3584 dwords: coef frags
#define WL_OFF TBLB_DWORDS

static __device__ __forceinline__ short bf16b(float f) {
  __bf16 h = (__bf16)f;
  return __builtin_bit_cast(short, h);
}

// ---- monomial id space: 0..164 order3 lex (i<=j<=k), 165..209 order2 lex,
//      210..218 order1, 219 = zero ----
constexpr int pidx(int i, int j) { return 9*i - i*(i-1)/2 + (j - i); }

struct MonoGF { unsigned char g, f; };   // value = G[g]*F[f]; g45=1; f9=1, f10=zero
constexpr MonoGF mono_gf(int id) {
  if (id < 165) {
    int s = 0;
    for (int i = 0; i < 9; ++i)
      for (int j = i; j < 9; ++j)
        for (int k = j; k < 9; ++k) {
          if (s == id) return MonoGF{(unsigned char)pidx(i,j), (unsigned char)k};
          ++s;
        }
  } else if (id < 210) {
    int s = 165;
    for (int i = 0; i < 9; ++i)
      for (int j = i; j < 9; ++j) {
        if (s == id) return MonoGF{(unsigned char)pidx(i,j), (unsigned char)9};
        ++s;
      }
  } else if (id < 219) {
    return MonoGF{45, (unsigned char)(id - 210)};
  }
  return MonoGF{45, 10};
}

struct PairTab { short m0[NPOS], m1[NPOS]; };
constexpr PairTab make_pairtab() {
  PairTab P{};
  int pos = 0;
  short singles3[32]{}; int ns3 = 0;
  int id = 0;
  for (int i = 0; i < 9; ++i)
    for (int j = i; j < 9; ++j) {
      int sz = 9 - j;
      int base = id;
      int t = 0;
      for (; t + 1 < sz; t += 2) { P.m0[pos] = (short)(base+t); P.m1[pos] = (short)(base+t+1); ++pos; }
      if (t < sz) singles3[ns3++] = (short)(base + t);
      id += sz;
    }
  int u = 0;
  for (; u + 1 < ns3; u += 2) { P.m0[pos] = singles3[u]; P.m1[pos] = singles3[u+1]; ++pos; }
  short left3 = (u < ns3) ? singles3[u] : (short)-1;
  int o2 = 165;
  for (; o2 + 1 < 210; o2 += 2) { P.m0[pos] = (short)o2; P.m1[pos] = (short)(o2+1); ++pos; }
  short left2 = (o2 < 210) ? (short)o2 : (short)-1;
  if (left3 >= 0 && left2 >= 0) { P.m0[pos] = left3; P.m1[pos] = left2; ++pos; }
  int o1 = 210;
  for (; o1 + 1 < 219; o1 += 2) { P.m0[pos] = (short)o1; P.m1[pos] = (short)(o1+1); ++pos; }
  P.m0[pos] = 218; P.m1[pos] = 219; ++pos;
  for (; pos < NPOS; ++pos) { P.m0[pos] = 219; P.m1[pos] = 219; }
  return P;
}
static constexpr PairTab PT = make_pairtab();

struct DecTab {
  unsigned short b3[165][6]; unsigned char c3[165];
  unsigned short b2[45][2];  unsigned char c2[45];
};
constexpr DecTab make_dectab() {
  DecTab D{};
  int s = 0;
  for (int i = 0; i < 9; ++i)
    for (int j = i; j < 9; ++j)
      for (int k = j; k < 9; ++k) {
        int pm[6][3] = {{i,j,k},{i,k,j},{j,i,k},{j,k,i},{k,i,j},{k,j,i}};
        int cnt = 0;
        for (int q = 0; q < 6; ++q) {
          bool dup = false;
          for (int r = 0; r < q; ++r)
            if (pm[r][0]==pm[q][0] && pm[r][1]==pm[q][1] && pm[r][2]==pm[q][2]) dup = true;
          if (!dup) { D.b3[s][cnt] = (unsigned short)((pm[q][0]*9 + pm[q][1])*9 + pm[q][2]); ++cnt; }
        }
        D.c3[s] = (unsigned char)cnt; ++s;
      }
  s = 0;
  for (int i = 0; i < 9; ++i)
    for (int j = i; j < 9; ++j) {
      D.b2[s][0] = (unsigned short)(i*9 + j);
      D.b2[s][1] = (unsigned short)(j*9 + i);
      D.c2[s] = (unsigned char)((i == j) ? 1 : 2); ++s;
    }
  return D;
}
static constexpr DecTab DT = make_dectab();

static __device__ __forceinline__ float coefval(int id, int col,
    const float* U1_0, const float* U2_0, const float* U3_0,
    const float* U1_1, const float* U2_1, const float* U3_1) {
  if (id < 165) {
    if (col < 12 || col >= 24) return 0.f;
    int mp = (col - 12) / 3, p = (col - 12) % 3;
    float acc = 0.f;
    int cnt = DT.c3[id];
    for (int q = 0; q < cnt; ++q) {
      int base = DT.b3[id][q];
      acc += (mp == 0) ? U3_0[base*3 + p] : U3_1[base*9 + (mp-1)*3 + p];
    }
    return acc;
  } else if (id < 210) {
    if (col < 4 || col >= 12) return 0.f;
    int mp = (col - 4) / 2, p = (col - 4) % 2;
    int s2 = id - 165;
    float acc = 0.f;
    int cnt = DT.c2[s2];
    for (int q = 0; q < cnt; ++q) {
      int base = DT.b2[s2][q];
      acc += (mp == 0) ? U2_0[base*2 + p] : U2_1[(base*3 + (mp-1))*2 + p];
    }
    return acc;
  } else if (id < 219) {
    int i = id - 210;
    if (col == 0) return U1_0[i];
    if (col < 4) return U1_1[i*3 + (col-1)];
    return 0.f;
  }
  return 0.f;
}

template<int POS>
static __device__ __forceinline__ float monoPos(const float* P45, const float* xr, bool ks1) {
  constexpr MonoGF A = mono_gf(PT.m0[POS]);
  constexpr MonoGF B = mono_gf(PT.m1[POS]);
  if constexpr (A.f == 10 && B.f == 10) {
    return 0.0f;
  } else if constexpr (B.f == 10) {
    float va = (A.g == 45) ? 1.0f : P45[A.g];
    if constexpr (A.f != 9) va *= xr[A.f];
    return ks1 ? 0.0f : va;
  } else if constexpr (A.f == 10) {
    float vb = (B.g == 45) ? 1.0f : P45[B.g];
    if constexpr (B.f != 9) vb *= xr[B.f];
    return ks1 ? vb : 0.0f;
  } else {
    float gv;
    if constexpr (A.g == B.g) gv = (A.g == 45) ? 1.0f : P45[A.g];
    else {
      float ga = (A.g == 45) ? 1.0f : P45[A.g];
      float gb = (B.g == 45) ? 1.0f : P45[B.g];
      gv = ks1 ? gb : ga;
    }
    if constexpr (A.f == 9 && B.f == 9) return gv;
    else if constexpr (A.f == B.f) return gv * xr[A.f];
    else {
      float fa = (A.f == 9) ? 1.0f : xr[A.f];
      float fb = (B.f == 9) ? 1.0f : xr[B.f];
      return gv * (ks1 ? fb : fa);
    }
  }
}

template<int T>
static __device__ __forceinline__ void k_steps(const float* P45, const float* xr, bool ks1,
                                               const unsigned int* lds_b, int lane, f32x16& acc) {
  if constexpr (T < NSTEP) {
    float m[8];
    m[0]=monoPos<T*8+0>(P45,xr,ks1); m[1]=monoPos<T*8+1>(P45,xr,ks1);
    m[2]=monoPos<T*8+2>(P45,xr,ks1); m[3]=monoPos<T*8+3>(P45,xr,ks1);
    m[4]=monoPos<T*8+4>(P45,xr,ks1); m[5]=monoPos<T*8+5>(P45,xr,ks1);
    m[6]=monoPos<T*8+6>(P45,xr,ks1); m[7]=monoPos<T*8+7>(P45,xr,ks1);
    short8 mf;
    mf[0]=bf16b(m[0]); mf[1]=bf16b(m[1]); mf[2]=bf16b(m[2]); mf[3]=bf16b(m[3]);
    mf[4]=bf16b(m[4]); mf[5]=bf16b(m[5]); mf[6]=bf16b(m[6]); mf[7]=bf16b(m[7]);
    short8 cf = *(const short8*)&lds_b[(T*64 + lane)*4];
    acc = __builtin_amdgcn_mfma_f32_32x32x16_bf16(cf, mf, acc, 0, 0, 0);
    k_steps<T+1>(P45, xr, ks1, lds_b, lane, acc);
  }
}

// ---- build kernel: coef frags (PT order) + Wlin B-frags ----
__global__ __launch_bounds__(64) void build_tables_kernel(
    const float* __restrict__ U1_0, const float* __restrict__ U2_0, const float* __restrict__ U3_0,
    const float* __restrict__ U1_1, const float* __restrict__ U2_1, const float* __restrict__ U3_1,
    const float* __restrict__ Wl0, const float* __restrict__ Wl1,
    unsigned int* __restrict__ tbl) {
  const int b = blockIdx.x, l = threadIdx.x;
  const int col = l & 31, ksb = l >> 5;
  if (b < NSTEP) {
    const int ft = b;
    #pragma unroll
    for (int d = 0; d < 4; ++d) {
      int pos0 = ft*8 + 2*d;
      int id0  = ksb ? PT.m1[pos0]     : PT.m0[pos0];
      int id1  = ksb ? PT.m1[pos0 + 1] : PT.m0[pos0 + 1];
      unsigned short lo = (unsigned short)bf16b(coefval(id0, col, U1_0,U2_0,U3_0,U1_1,U2_1,U3_1));
      unsigned short hi = (unsigned short)bf16b(coefval(id1, col, U1_0,U2_0,U3_0,U1_1,U2_1,U3_1));
      tbl[(ft*64 + l)*4 + d] = ((unsigned int)hi << 16) | lo;
    }
  } else {
    const int u = b - NSTEP;            // 0..63 : (g, ntile, step)
    const int g = u >> 5, u5 = u & 31, nt = u5 >> 3, st = u5 & 7;
    const float* W = g ? Wl1 : Wl0;     // [c][d] row-major; k = c
    #pragma unroll
    for (int d = 0; d < 4; ++d) {
      int k = st*16 + ksb*8 + 2*d;
      unsigned short lo = (unsigned short)bf16b(W[(long)k*128     + nt*32 + col]);
      unsigned short hi = (unsigned short)bf16b(W[(long)(k+1)*128 + nt*32 + col]);
      tbl[WL_OFF + u*256 + l*4 + d] = ((unsigned int)hi << 16) | lo;
    }
  }
}

// ---- main kernel ----
__global__ __launch_bounds__(512, 2) void epbb_mfma_kernel(
    const float* __restrict__ xg, const float* __restrict__ na, const float* __restrict__ sc,
    const float* __restrict__ W1_0, const float* __restrict__ W2_0, const float* __restrict__ W3_0,
    const float* __restrict__ W1_1, const float* __restrict__ W2_1, const float* __restrict__ W3_1,
    const unsigned int* __restrict__ tbl,
    float* __restrict__ out) {
  __shared__ __align__(16) unsigned int lds_b[TBLB_DWORDS];  // 14336 B
  __shared__ __align__(16) short lds_yA[2][8][136];          // 4352 B

  const int tid  = threadIdx.x;
  const int lane = tid & 63;
  const int w    = tid >> 6;
  const int ks   = lane >> 5;
  const bool ks1 = (ks != 0);
  const int n0   = blockIdx.x * 2;

  const int nw = w >> 2;
  const int n  = n0 + nw;
  const int c0 = (w & 3) * 32;
  const int cl = c0 + (lane & 31);

  // entry loads: x, na->e, weights, sc (all issued before the first barrier)
  const float* xp = xg + ((long)(n*128 + cl))*9;
  float xr[9];
  #pragma unroll
  for (int q = 0; q < 9; ++q) xr[q] = xp[q];

  int e = 0;
  #pragma unroll
  for (int q = 0; q < 10; ++q) e = (na[(long)n*10 + q] > 0.5f) ? q : e;
  const float w10  = W1_0[e*128 + cl];
  const float w20a = W2_0[(e*2+0)*128 + cl], w20b = W2_0[(e*2+1)*128 + cl];
  const float w30a = W3_0[(e*3+0)*128 + cl], w30b = W3_0[(e*3+1)*128 + cl], w30c = W3_0[(e*3+2)*128 + cl];
  const float w11  = W1_1[e*128 + cl];
  const float w21a = W2_1[(e*2+0)*128 + cl], w21b = W2_1[(e*2+1)*128 + cl];
  const float w31a = W3_1[(e*3+0)*128 + cl], w31b = W3_1[(e*3+1)*128 + cl], w31c = W3_1[(e*3+2)*128 + cl];

  // sc preload per store-role (g = w>>2, nt = w&3)
  const int g  = w >> 2;
  const int nt = w & 3;
  const int d  = nt*32 + (lane & 31);
  float scR[4] = {0.f, 0.f, 0.f, 0.f};
  if (g == 0) {
    if (ks == 0) {
      scR[0] = sc[(long)(n0+0)*512 + d];
      scR[1] = sc[(long)(n0+1)*512 + d];
    }
  } else {
    if (ks == 0) {
      #pragma unroll
      for (int r = 0; r < 4; ++r) scR[r] = sc[(long)(n0 + (r & 1))*512 + 128 + 3*d + (r >> 1)];
    } else {
      scR[0] = sc[(long)(n0+0)*512 + 128 + 3*d + 2];
      scR[1] = sc[(long)(n0+1)*512 + 128 + 3*d + 2];
    }
  }

  // pair products (uniform across reps; part of real phase1 cost? cheap: 45 mul)
  float P45[45];
  {
    int s = 0;
    #pragma unroll
    for (int i = 0; i < 9; ++i)
      #pragma unroll
      for (int j = i; j < 9; ++j) { P45[s] = xr[i]*xr[j]; ++s; }
  }

  // ======== REPS x full body ========
  f32x16 z;
  #pragma unroll 1
  for (int rep = 0; rep < REPS; ++rep) {
    int off = 0;
    asm volatile("" : "+v"(off));      // defeat LICM of global reads per rep

    // staging: coef frags -> LDS
    for (int q = tid; q < TBLB_DWORDS; q += 512) lds_b[q] = tbl[q + off];

    f32x16 acc;
    #pragma unroll
    for (int q = 0; q < 16; ++q) acc[q] = 0.f;

    __syncthreads();
    k_steps<0>(P45, xr, ks1, lds_b, lane, acc);

    // phase 2: in-register weighted path reduction
    float p0, p1, p2, p3;
    if (ks == 0) {
      p0 = w10*acc[0];
      p1 = w11*acc[1] + w31b*acc[8]  + w31c*acc[9];
      p2 = w11*acc[2] + w21a*acc[4]  + w21b*acc[5] + w31a*acc[10] + w31b*acc[11];
      p3 = w11*acc[3] + w21a*acc[6]  + w21b*acc[7];
    } else {
      p0 = w20a*acc[0] + w20b*acc[1] + w30a*acc[4] + w30b*acc[5] + w30c*acc[6];
      p1 = w21a*acc[2] + w21b*acc[3] + w31a*acc[7];
      p2 = w31c*acc[8];
      p3 = w31a*acc[9] + w31b*acc[10] + w31c*acc[11];
    }
    const float y0 = p0 + __shfl_xor(p0, 32, 64);
    const float y1 = p1 + __shfl_xor(p1, 32, 64);
    const float y2 = p2 + __shfl_xor(p2, 32, 64);
    const float y3 = p3 + __shfl_xor(p3, 32, 64);

    if (ks == 0) {
      lds_yA[0][nw][cl]     = bf16b(y0);
      lds_yA[1][nw][cl]     = bf16b(y1);
    } else {
      lds_yA[1][2 + nw][cl] = bf16b(y2);
      lds_yA[1][4 + nw][cl] = bf16b(y3);
    }
    __syncthreads();

    // phase 3: z = y * Wlin via padded MFMA (prepacked B-frags from tbl)
    #pragma unroll
    for (int q = 0; q < 16; ++q) z[q] = 0.f;
    const unsigned int* bw = tbl + WL_OFF + ((g*4 + nt)*8)*256 + off;
    #pragma unroll
    for (int st = 0; st < 8; ++st) {
      short8 af = *(const short8*)&lds_yA[g][lane & 7][st*16 + ks*8];
      short8 bf = *(const short8*)&bw[st*256 + lane*4];
      z = __builtin_amdgcn_mfma_f32_32x32x16_bf16(af, bf, z, 0, 0, 0);
    }
    // opaque: keep z live, block cross-rep folding
    #pragma unroll
    for (int q = 0; q < 16; ++q) { float t = z[q]; asm volatile("" : "+v"(t)); z[q] = t; }
  }
  // ======== end body loop ========

  const float inv = 0.088388347648318447f;   // 1/sqrt(128)
  if (g == 0) {
    if (ks == 0) {
      #pragma unroll
      for (int r = 0; r < 2; ++r) {
        long o = (long)(n0 + r)*512 + d;
        out[o] = z[r]*inv + scR[r];
      }
    }
  } else {
    if (ks == 0) {
      #pragma unroll
      for (int r = 0; r < 4; ++r) {
        long o = (long)(n0 + (r & 1))*512 + 128 + 3*d + (r >> 1);
        out[o] = z[r]*inv + scR[r];
      }
    } else {
      #pragma unroll
      for (int r = 0; r < 2; ++r) {
        long o = (long)(n0 + r)*512 + 128 + 3*d + 2;
        out[o] = z[r]*inv + scR[r];
      }
    }
  }
}

extern "C" void kernel_launch(void* const* d_in, const int* in_sizes, int n_in,
                              void* d_out, int out_size, void* d_ws, size_t ws_size,
                              hipStream_t stream) {
  const float* xg   = (const float*)d_in[0];
  const float* na   = (const float*)d_in[1];
  const float* sc   = (const float*)d_in[2];
  const float* U1_0 = (const float*)d_in[3];
  const float* W1_0 = (const float*)d_in[4];
  const float* U2_0 = (const float*)d_in[5];
  const float* W2_0 = (const float*)d_in[6];
  const float* U3_0 = (const float*)d_in[7];
  const float* W3_0 = (const float*)d_in[8];
  const float* Wl0  = (const float*)d_in[9];
  const float* U1_1 = (const float*)d_in[10];
  const float* W1_1 = (const float*)d_in[11];
  const float* U2_1 = (const float*)d_in[12];
  const float* W2_1 = (const float*)d_in[13];
  const float* U3_1 = (const float*)d_in[14];
  const float* W3_1 = (const float*)d_in[15];
  const float* Wl1  = (const float*)d_in[16];

  unsigned int* tbl = (unsigned int*)d_ws;     // 79872 B
  const int N = in_sizes[0] / (128 * 9);

  hipLaunchKernelGGL(build_tables_kernel, dim3(NSTEP + 64), dim3(64), 0, stream,
                     U1_0, U2_0, U3_0, U1_1, U2_1, U3_1, Wl0, Wl1, tbl);
  hipLaunchKernelGGL(epbb_mfma_kernel, dim3(N/2), dim3(512), 0, stream,
                     xg, na, sc, W1_0, W2_0, W3_0, W1_1, W2_1, W3_1, tbl,
                     (float*)d_out);
}

// Round 12
// 24.234 us; speedup vs baseline: 2.0191x; 2.0191x over previous
//
#include <hip/hip_runtime.h>

// EquivariantProductBasisBlock (MACE symmetric contraction, nu=3) on gfx950.
//
// R12 = R11 body at REPS=1 (real kernel):
//  - branchless monomials via PT pairing (no ks-divergent double-issue),
//  - DUAL MFMA accumulators (even/odd K-steps) to break the 14-deep serial
//    accumulate chain into 2x7, merged in phase 2,
//  - early weight + sc preloads; build kernel packs coef (PT order) + Wlin.
// Verified mapping (R5/R11): mfma(coef,mono) -> D[pc][ch], lane ch=lane&31,
// path-col rr=(r&3)+8*(r>>2)+4*ks; phase3 padded GEMM rows g0{nv},g1{2(mp-1)+nv}.

typedef __attribute__((ext_vector_type(8))) short short8;
typedef __attribute__((ext_vector_type(16))) float f32x16;

#define NSTEP 14
#define NPOS (NSTEP*8)              // 112 k-pair positions
#define TBLB_DWORDS (NSTEP*64*4)    // 3584 dwords: coef frags
#define WL_OFF TBLB_DWORDS

static __device__ __forceinline__ short bf16b(float f) {
  __bf16 h = (__bf16)f;
  return __builtin_bit_cast(short, h);
}

// ---- monomial id space: 0..164 order3 lex (i<=j<=k), 165..209 order2 lex,
//      210..218 order1, 219 = zero ----
constexpr int pidx(int i, int j) { return 9*i - i*(i-1)/2 + (j - i); }

struct MonoGF { unsigned char g, f; };   // value = G[g]*F[f]; g45=1; f9=1, f10=zero
constexpr MonoGF mono_gf(int id) {
  if (id < 165) {
    int s = 0;
    for (int i = 0; i < 9; ++i)
      for (int j = i; j < 9; ++j)
        for (int k = j; k < 9; ++k) {
          if (s == id) return MonoGF{(unsigned char)pidx(i,j), (unsigned char)k};
          ++s;
        }
  } else if (id < 210) {
    int s = 165;
    for (int i = 0; i < 9; ++i)
      for (int j = i; j < 9; ++j) {
        if (s == id) return MonoGF{(unsigned char)pidx(i,j), (unsigned char)9};
        ++s;
      }
  } else if (id < 219) {
    return MonoGF{45, (unsigned char)(id - 210)};
  }
  return MonoGF{45, 10};
}

struct PairTab { short m0[NPOS], m1[NPOS]; };
constexpr PairTab make_pairtab() {
  PairTab P{};
  int pos = 0;
  short singles3[32]{}; int ns3 = 0;
  int id = 0;
  for (int i = 0; i < 9; ++i)
    for (int j = i; j < 9; ++j) {
      int sz = 9 - j;
      int base = id;
      int t = 0;
      for (; t + 1 < sz; t += 2) { P.m0[pos] = (short)(base+t); P.m1[pos] = (short)(base+t+1); ++pos; }
      if (t < sz) singles3[ns3++] = (short)(base + t);
      id += sz;
    }
  int u = 0;
  for (; u + 1 < ns3; u += 2) { P.m0[pos] = singles3[u]; P.m1[pos] = singles3[u+1]; ++pos; }
  short left3 = (u < ns3) ? singles3[u] : (short)-1;
  int o2 = 165;
  for (; o2 + 1 < 210; o2 += 2) { P.m0[pos] = (short)o2; P.m1[pos] = (short)(o2+1); ++pos; }
  short left2 = (o2 < 210) ? (short)o2 : (short)-1;
  if (left3 >= 0 && left2 >= 0) { P.m0[pos] = left3; P.m1[pos] = left2; ++pos; }
  int o1 = 210;
  for (; o1 + 1 < 219; o1 += 2) { P.m0[pos] = (short)o1; P.m1[pos] = (short)(o1+1); ++pos; }
  P.m0[pos] = 218; P.m1[pos] = 219; ++pos;
  for (; pos < NPOS; ++pos) { P.m0[pos] = 219; P.m1[pos] = 219; }
  return P;
}
static constexpr PairTab PT = make_pairtab();

struct DecTab {
  unsigned short b3[165][6]; unsigned char c3[165];
  unsigned short b2[45][2];  unsigned char c2[45];
};
constexpr DecTab make_dectab() {
  DecTab D{};
  int s = 0;
  for (int i = 0; i < 9; ++i)
    for (int j = i; j < 9; ++j)
      for (int k = j; k < 9; ++k) {
        int pm[6][3] = {{i,j,k},{i,k,j},{j,i,k},{j,k,i},{k,i,j},{k,j,i}};
        int cnt = 0;
        for (int q = 0; q < 6; ++q) {
          bool dup = false;
          for (int r = 0; r < q; ++r)
            if (pm[r][0]==pm[q][0] && pm[r][1]==pm[q][1] && pm[r][2]==pm[q][2]) dup = true;
          if (!dup) { D.b3[s][cnt] = (unsigned short)((pm[q][0]*9 + pm[q][1])*9 + pm[q][2]); ++cnt; }
        }
        D.c3[s] = (unsigned char)cnt; ++s;
      }
  s = 0;
  for (int i = 0; i < 9; ++i)
    for (int j = i; j < 9; ++j) {
      D.b2[s][0] = (unsigned short)(i*9 + j);
      D.b2[s][1] = (unsigned short)(j*9 + i);
      D.c2[s] = (unsigned char)((i == j) ? 1 : 2); ++s;
    }
  return D;
}
static constexpr DecTab DT = make_dectab();

static __device__ __forceinline__ float coefval(int id, int col,
    const float* U1_0, const float* U2_0, const float* U3_0,
    const float* U1_1, const float* U2_1, const float* U3_1) {
  if (id < 165) {
    if (col < 12 || col >= 24) return 0.f;
    int mp = (col - 12) / 3, p = (col - 12) % 3;
    float acc = 0.f;
    int cnt = DT.c3[id];
    for (int q = 0; q < cnt; ++q) {
      int base = DT.b3[id][q];
      acc += (mp == 0) ? U3_0[base*3 + p] : U3_1[base*9 + (mp-1)*3 + p];
    }
    return acc;
  } else if (id < 210) {
    if (col < 4 || col >= 12) return 0.f;
    int mp = (col - 4) / 2, p = (col - 4) % 2;
    int s2 = id - 165;
    float acc = 0.f;
    int cnt = DT.c2[s2];
    for (int q = 0; q < cnt; ++q) {
      int base = DT.b2[s2][q];
      acc += (mp == 0) ? U2_0[base*2 + p] : U2_1[(base*3 + (mp-1))*2 + p];
    }
    return acc;
  } else if (id < 219) {
    int i = id - 210;
    if (col == 0) return U1_0[i];
    if (col < 4) return U1_1[i*3 + (col-1)];
    return 0.f;
  }
  return 0.f;
}

template<int POS>
static __device__ __forceinline__ float monoPos(const float* P45, const float* xr, bool ks1) {
  constexpr MonoGF A = mono_gf(PT.m0[POS]);
  constexpr MonoGF B = mono_gf(PT.m1[POS]);
  if constexpr (A.f == 10 && B.f == 10) {
    return 0.0f;
  } else if constexpr (B.f == 10) {
    float va = (A.g == 45) ? 1.0f : P45[A.g];
    if constexpr (A.f != 9) va *= xr[A.f];
    return ks1 ? 0.0f : va;
  } else if constexpr (A.f == 10) {
    float vb = (B.g == 45) ? 1.0f : P45[B.g];
    if constexpr (B.f != 9) vb *= xr[B.f];
    return ks1 ? vb : 0.0f;
  } else {
    float gv;
    if constexpr (A.g == B.g) gv = (A.g == 45) ? 1.0f : P45[A.g];
    else {
      float ga = (A.g == 45) ? 1.0f : P45[A.g];
      float gb = (B.g == 45) ? 1.0f : P45[B.g];
      gv = ks1 ? gb : ga;
    }
    if constexpr (A.f == 9 && B.f == 9) return gv;
    else if constexpr (A.f == B.f) return gv * xr[A.f];
    else {
      float fa = (A.f == 9) ? 1.0f : xr[A.f];
      float fb = (B.f == 9) ? 1.0f : xr[B.f];
      return gv * (ks1 ? fb : fa);
    }
  }
}

// one K-step MFMA into the given accumulator
template<int T>
static __device__ __forceinline__ void k_step_one(const float* P45, const float* xr, bool ks1,
                                                  const unsigned int* lds_b, int lane, f32x16& acc) {
  float m[8];
  m[0]=monoPos<T*8+0>(P45,xr,ks1); m[1]=monoPos<T*8+1>(P45,xr,ks1);
  m[2]=monoPos<T*8+2>(P45,xr,ks1); m[3]=monoPos<T*8+3>(P45,xr,ks1);
  m[4]=monoPos<T*8+4>(P45,xr,ks1); m[5]=monoPos<T*8+5>(P45,xr,ks1);
  m[6]=monoPos<T*8+6>(P45,xr,ks1); m[7]=monoPos<T*8+7>(P45,xr,ks1);
  short8 mf;
  mf[0]=bf16b(m[0]); mf[1]=bf16b(m[1]); mf[2]=bf16b(m[2]); mf[3]=bf16b(m[3]);
  mf[4]=bf16b(m[4]); mf[5]=bf16b(m[5]); mf[6]=bf16b(m[6]); mf[7]=bf16b(m[7]);
  short8 cf = *(const short8*)&lds_b[(T*64 + lane)*4];
  acc = __builtin_amdgcn_mfma_f32_32x32x16_bf16(cf, mf, acc, 0, 0, 0);
}

// dual-chain K-loop: even steps -> acc0, odd steps -> acc1 (2x7 dep chains)
template<int T>
static __device__ __forceinline__ void k_steps2(const float* P45, const float* xr, bool ks1,
                                                const unsigned int* lds_b, int lane,
                                                f32x16& acc0, f32x16& acc1) {
  if constexpr (T < NSTEP) {
    k_step_one<T>(P45, xr, ks1, lds_b, lane, acc0);
    if constexpr (T + 1 < NSTEP) k_step_one<T+1>(P45, xr, ks1, lds_b, lane, acc1);
    k_steps2<T+2>(P45, xr, ks1, lds_b, lane, acc0, acc1);
  }
}

// ---- build kernel: coef frags (PT order) + Wlin B-frags ----
__global__ __launch_bounds__(64) void build_tables_kernel(
    const float* __restrict__ U1_0, const float* __restrict__ U2_0, const float* __restrict__ U3_0,
    const float* __restrict__ U1_1, const float* __restrict__ U2_1, const float* __restrict__ U3_1,
    const float* __restrict__ Wl0, const float* __restrict__ Wl1,
    unsigned int* __restrict__ tbl) {
  const int b = blockIdx.x, l = threadIdx.x;
  const int col = l & 31, ksb = l >> 5;
  if (b < NSTEP) {
    const int ft = b;
    #pragma unroll
    for (int d = 0; d < 4; ++d) {
      int pos0 = ft*8 + 2*d;
      int id0  = ksb ? PT.m1[pos0]     : PT.m0[pos0];
      int id1  = ksb ? PT.m1[pos0 + 1] : PT.m0[pos0 + 1];
      unsigned short lo = (unsigned short)bf16b(coefval(id0, col, U1_0,U2_0,U3_0,U1_1,U2_1,U3_1));
      unsigned short hi = (unsigned short)bf16b(coefval(id1, col, U1_0,U2_0,U3_0,U1_1,U2_1,U3_1));
      tbl[(ft*64 + l)*4 + d] = ((unsigned int)hi << 16) | lo;
    }
  } else {
    const int u = b - NSTEP;            // 0..63 : (g, ntile, step)
    const int g = u >> 5, u5 = u & 31, nt = u5 >> 3, st = u5 & 7;
    const float* W = g ? Wl1 : Wl0;     // [c][d] row-major; k = c
    #pragma unroll
    for (int d = 0; d < 4; ++d) {
      int k = st*16 + ksb*8 + 2*d;
      unsigned short lo = (unsigned short)bf16b(W[(long)k*128     + nt*32 + col]);
      unsigned short hi = (unsigned short)bf16b(W[(long)(k+1)*128 + nt*32 + col]);
      tbl[WL_OFF + u*256 + l*4 + d] = ((unsigned int)hi << 16) | lo;
    }
  }
}

// ---- main kernel ----
__global__ __launch_bounds__(512, 2) void epbb_mfma_kernel(
    const float* __restrict__ xg, const float* __restrict__ na, const float* __restrict__ sc,
    const float* __restrict__ W1_0, const float* __restrict__ W2_0, const float* __restrict__ W3_0,
    const float* __restrict__ W1_1, const float* __restrict__ W2_1, const float* __restrict__ W3_1,
    const unsigned int* __restrict__ tbl,
    float* __restrict__ out) {
  __shared__ __align__(16) unsigned int lds_b[TBLB_DWORDS];  // 14336 B
  __shared__ __align__(16) short lds_yA[2][8][136];          // 4352 B

  const int tid  = threadIdx.x;
  const int lane = tid & 63;
  const int w    = tid >> 6;
  const int ks   = lane >> 5;
  const bool ks1 = (ks != 0);
  const int n0   = blockIdx.x * 2;

  const int nw = w >> 2;
  const int n  = n0 + nw;
  const int c0 = (w & 3) * 32;
  const int cl = c0 + (lane & 31);

  // entry loads: x, na->e, weights, sc (all issued before the first barrier)
  const float* xp = xg + ((long)(n*128 + cl))*9;
  float xr[9];
  #pragma unroll
  for (int q = 0; q < 9; ++q) xr[q] = xp[q];

  int e = 0;
  #pragma unroll
  for (int q = 0; q < 10; ++q) e = (na[(long)n*10 + q] > 0.5f) ? q : e;
  const float w10  = W1_0[e*128 + cl];
  const float w20a = W2_0[(e*2+0)*128 + cl], w20b = W2_0[(e*2+1)*128 + cl];
  const float w30a = W3_0[(e*3+0)*128 + cl], w30b = W3_0[(e*3+1)*128 + cl], w30c = W3_0[(e*3+2)*128 + cl];
  const float w11  = W1_1[e*128 + cl];
  const float w21a = W2_1[(e*2+0)*128 + cl], w21b = W2_1[(e*2+1)*128 + cl];
  const float w31a = W3_1[(e*3+0)*128 + cl], w31b = W3_1[(e*3+1)*128 + cl], w31c = W3_1[(e*3+2)*128 + cl];

  // sc preload per store-role
  const int g  = w >> 2;
  const int nt = w & 3;
  const int d  = nt*32 + (lane & 31);
  float scR[4] = {0.f, 0.f, 0.f, 0.f};
  if (g == 0) {
    if (ks == 0) {
      scR[0] = sc[(long)(n0+0)*512 + d];
      scR[1] = sc[(long)(n0+1)*512 + d];
    }
  } else {
    if (ks == 0) {
      #pragma unroll
      for (int r = 0; r < 4; ++r) scR[r] = sc[(long)(n0 + (r & 1))*512 + 128 + 3*d + (r >> 1)];
    } else {
      scR[0] = sc[(long)(n0+0)*512 + 128 + 3*d + 2];
      scR[1] = sc[(long)(n0+1)*512 + 128 + 3*d + 2];
    }
  }

  // staging: coef frags -> LDS (coalesced; overlaps the loads above)
  for (int q = tid; q < TBLB_DWORDS; q += 512) lds_b[q] = tbl[q];

  // pair products P[i,j] = xr[i]*xr[j], i<=j (shared by both ks roles)
  float P45[45];
  {
    int s = 0;
    #pragma unroll
    for (int i = 0; i < 9; ++i)
      #pragma unroll
      for (int j = i; j < 9; ++j) { P45[s] = xr[i]*xr[j]; ++s; }
  }

  f32x16 acc0, acc1;
  #pragma unroll
  for (int q = 0; q < 16; ++q) { acc0[q] = 0.f; acc1[q] = 0.f; }

  __syncthreads();
  k_steps2<0>(P45, xr, ks1, lds_b, lane, acc0, acc1);

  // merge dual chains
  f32x16 acc;
  #pragma unroll
  for (int q = 0; q < 16; ++q) acc[q] = acc0[q] + acc1[q];

  // phase 2: in-register weighted path reduction
  float p0, p1, p2, p3;
  if (ks == 0) {
    p0 = w10*acc[0];
    p1 = w11*acc[1] + w31b*acc[8]  + w31c*acc[9];
    p2 = w11*acc[2] + w21a*acc[4]  + w21b*acc[5] + w31a*acc[10] + w31b*acc[11];
    p3 = w11*acc[3] + w21a*acc[6]  + w21b*acc[7];
  } else {
    p0 = w20a*acc[0] + w20b*acc[1] + w30a*acc[4] + w30b*acc[5] + w30c*acc[6];
    p1 = w21a*acc[2] + w21b*acc[3] + w31a*acc[7];
    p2 = w31c*acc[8];
    p3 = w31a*acc[9] + w31b*acc[10] + w31c*acc[11];
  }
  const float y0 = p0 + __shfl_xor(p0, 32, 64);
  const float y1 = p1 + __shfl_xor(p1, 32, 64);
  const float y2 = p2 + __shfl_xor(p2, 32, 64);
  const float y3 = p3 + __shfl_xor(p3, 32, 64);

  if (ks == 0) {
    lds_yA[0][nw][cl]     = bf16b(y0);
    lds_yA[1][nw][cl]     = bf16b(y1);
  } else {
    lds_yA[1][2 + nw][cl] = bf16b(y2);
    lds_yA[1][4 + nw][cl] = bf16b(y3);
  }
  __syncthreads();

  // phase 3: z = y * Wlin via padded MFMA (prepacked B-frags from tbl)
  f32x16 z;
  #pragma unroll
  for (int q = 0; q < 16; ++q) z[q] = 0.f;
  const unsigned int* bw = tbl + WL_OFF + ((g*4 + nt)*8)*256;
  #pragma unroll
  for (int st = 0; st < 8; ++st) {
    short8 af = *(const short8*)&lds_yA[g][lane & 7][st*16 + ks*8];
    short8 bf = *(const short8*)&bw[st*256 + lane*4];
    z = __builtin_amdgcn_mfma_f32_32x32x16_bf16(af, bf, z, 0, 0, 0);
  }

  const float inv = 0.088388347648318447f;   // 1/sqrt(128)
  if (g == 0) {
    if (ks == 0) {
      #pragma unroll
      for (int r = 0; r < 2; ++r) {
        long o = (long)(n0 + r)*512 + d;
        out[o] = z[r]*inv + scR[r];
      }
    }
  } else {
    if (ks == 0) {
      #pragma unroll
      for (int r = 0; r < 4; ++r) {
        long o = (long)(n0 + (r & 1))*512 + 128 + 3*d + (r >> 1);
        out[o] = z[r]*inv + scR[r];
      }
    } else {
      #pragma unroll
      for (int r = 0; r < 2; ++r) {
        long o = (long)(n0 + r)*512 + 128 + 3*d + 2;
        out[o] = z[r]*inv + scR[r];
      }
    }
  }
}

extern "C" void kernel_launch(void* const* d_in, const int* in_sizes, int n_in,
                              void* d_out, int out_size, void* d_ws, size_t ws_size,
                              hipStream_t stream) {
  const float* xg   = (const float*)d_in[0];
  const float* na   = (const float*)d_in[1];
  const float* sc   = (const float*)d_in[2];
  const float* U1_0 = (const float*)d_in[3];
  const float* W1_0 = (const float*)d_in[4];
  const float* U2_0 = (const float*)d_in[5];
  const float* W2_0 = (const float*)d_in[6];
  const float* U3_0 = (const float*)d_in[7];
  const float* W3_0 = (const float*)d_in[8];
  const float* Wl0  = (const float*)d_in[9];
  const float* U1_1 = (const float*)d_in[10];
  const float* W1_1 = (const float*)d_in[11];
  const float* U2_1 = (const float*)d_in[12];
  const float* W2_1 = (const float*)d_in[13];
  const float* U3_1 = (const float*)d_in[14];
  const float* W3_1 = (const float*)d_in[15];
  const float* Wl1  = (const float*)d_in[16];

  unsigned int* tbl = (unsigned int*)d_ws;     // 79872 B
  const int N = in_sizes[0] / (128 * 9);

  hipLaunchKernelGGL(build_tables_kernel, dim3(NSTEP + 64), dim3(64), 0, stream,
                     U1_0, U2_0, U3_0, U1_1, U2_1, U3_1, Wl0, Wl1, tbl);
  hipLaunchKernelGGL(epbb_mfma_kernel, dim3(N/2), dim3(512), 0, stream,
                     xg, na, sc, W1_0, W2_0, W3_0, W1_1, W2_1, W3_1, tbl,
                     (float*)d_out);
}